// Round 8
// baseline (8786.252 us; speedup 1.0000x reference)
//
#include <hip/hip_runtime.h>
#include <hip/hip_bf16.h>

#define T_STEPS 800
#define BATCH   32
#define FEAT    161
#define UNITS   1024
#define CLIPV   20.0f
#define POLL_TIMEOUT 4096

typedef __attribute__((ext_vector_type(8))) short short8;
typedef __attribute__((ext_vector_type(4))) float f32x4;
typedef __attribute__((ext_vector_type(4))) unsigned int u32x4;
typedef unsigned short u16;
typedef unsigned int   u32;
typedef unsigned long long u64;

__device__ __forceinline__ float bf16_f(u16 u) {
    return __uint_as_float(((u32)u) << 16);
}
__device__ __forceinline__ u16 bf16_rn(float x) {
    __hip_bfloat16 b = __float2bfloat16(x);
    return *(u16*)&b;
}
__device__ __forceinline__ u64 ld_agent_u64(const u64* p) {
    return __hip_atomic_load(p, __ATOMIC_RELAXED, __HIP_MEMORY_SCOPE_AGENT);
}
__device__ __forceinline__ u32 ld_agent_u32(const u32* p) {
    return __hip_atomic_load(p, __ATOMIC_RELAXED, __HIP_MEMORY_SCOPE_AGENT);
}
__device__ __forceinline__ float ld_agent_f(const float* p) {
    return __hip_atomic_load(p, __ATOMIC_RELAXED, __HIP_MEMORY_SCOPE_AGENT);
}
__device__ __forceinline__ void st_agent_u32(u32* p, u32 v) {
    __hip_atomic_store(p, v, __ATOMIC_RELAXED, __HIP_MEMORY_SCOPE_AGENT);
}
__device__ __forceinline__ void st_agent_f(float* p, float v) {
    __hip_atomic_store(p, v, __ATOMIC_RELAXED, __HIP_MEMORY_SCOPE_AGENT);
}
__device__ __forceinline__ short8 ld_agent_b16x8(const u16* p) {
    union { u64 q[2]; short8 v; } u;
    u.q[0] = ld_agent_u64((const u64*)p);
    u.q[1] = ld_agent_u64((const u64*)p + 1);
    return u.v;
}
// --- XCD-local fast-path primitives: L1-bypass (sc0), L2-served ---
__device__ __forceinline__ u32x4 ld_sc0_u32x4(const u32* p) {
    u32x4 v;
    asm volatile("global_load_dwordx4 %0, %1, off sc0\n\t"
                 "s_waitcnt vmcnt(0)"
                 : "=&v"(v) : "v"(p) : "memory");
    return v;
}
__device__ __forceinline__ float ld_sc0_f(const float* p) {
    float v;
    asm volatile("global_load_dword %0, %1, off sc0\n\t"
                 "s_waitcnt vmcnt(0)"
                 : "=&v"(v) : "v"(p) : "memory");
    return v;
}
__device__ __forceinline__ void st_plain_u32(u32* p, u32 v) {
    asm volatile("global_store_dword %0, %1, off" :: "v"(p), "v"(v) : "memory");
}
__device__ __forceinline__ void st_plain_f(float* p, float v) {
    asm volatile("global_store_dword %0, %1, off" :: "v"(p), "v"(v) : "memory");
}
struct Q8 { f32x4 a, b, c, d, e, f, g, h; };
// 8 x 16B from one base (offsets 0/16, 128/144, 256/272, 384/400), one waitcnt
__device__ __forceinline__ Q8 ld_sc0_q8(const float* ab) {
    Q8 r;
    asm volatile(
        "global_load_dwordx4 %0, %8, off sc0\n\t"
        "global_load_dwordx4 %1, %8, off offset:16 sc0\n\t"
        "global_load_dwordx4 %2, %8, off offset:128 sc0\n\t"
        "global_load_dwordx4 %3, %8, off offset:144 sc0\n\t"
        "global_load_dwordx4 %4, %8, off offset:256 sc0\n\t"
        "global_load_dwordx4 %5, %8, off offset:272 sc0\n\t"
        "global_load_dwordx4 %6, %8, off offset:384 sc0\n\t"
        "global_load_dwordx4 %7, %8, off offset:400 sc0\n\t"
        "s_waitcnt vmcnt(0)"
        : "=&v"(r.a), "=&v"(r.b), "=&v"(r.c), "=&v"(r.d),
          "=&v"(r.e), "=&v"(r.f), "=&v"(r.g), "=&v"(r.h)
        : "v"(ab) : "memory");
    return r;
}

// ctrl (u32 words): 0..3 DEMOTE[g] | 16 NDONE | 24 FINDONE | 128..255 FLAGS | 256..383 LOC
#define C_DEMOTE  0
#define C_NDONE   16
#define C_FINDONE 24
#define C_FLAGS   128
#define C_LOC     256

// ---------------------------------------------------------------------------
__global__ __launch_bounds__(256) void init_ws(u32* ctrl) {
    int gid = blockIdx.x * 256 + threadIdx.x;
    if (gid < 512) st_agent_u32(ctrl + gid, 0u);
}

// ---------------------------------------------------------------------------
// Ut splits: U[k][u] fp32 -> Ut1/2/3[u][k] bf16 (hi/mid/lo, 24-bit total)
__global__ __launch_bounds__(256) void u_split_t(const float* __restrict__ U,
                                                 u16* __restrict__ Ut1,
                                                 u16* __restrict__ Ut2,
                                                 u16* __restrict__ Ut3) {
    __shared__ float tile[32][33];
    int bx = blockIdx.x, by = blockIdx.y;
    int lx = threadIdx.x & 31;
    int ly4 = (threadIdx.x >> 5) * 4;
    #pragma unroll
    for (int j = 0; j < 4; ++j)
        tile[ly4 + j][lx] = U[(size_t)(by * 32 + ly4 + j) * UNITS + bx * 32 + lx];
    __syncthreads();
    #pragma unroll
    for (int j = 0; j < 4; ++j) {
        float x = tile[lx][ly4 + j];
        size_t o = (size_t)(bx * 32 + ly4 + j) * UNITS + by * 32 + lx;
        u16 s1 = bf16_rn(x);  float r1 = x - bf16_f(s1);
        u16 s2 = bf16_rn(r1); float r2 = r1 - bf16_f(s2);
        u16 s3 = bf16_rn(r2);
        Ut1[o] = s1; Ut2[o] = s2; Ut3[o] = s3;
    }
}

// ---------------------------------------------------------------------------
__global__ __launch_bounds__(256) void xw_gemm(const float* __restrict__ inp,
                                               const float* __restrict__ W,
                                               const float* __restrict__ bias,
                                               float* __restrict__ xW) {
    __shared__ float xs[8 * FEAT];
    int t = blockIdx.x;
    int b0 = blockIdx.y * 8;
    int tid = threadIdx.x;

    for (int i = tid; i < 8 * FEAT; i += 256) {
        int j = i / FEAT;
        int f = i - j * FEAT;
        xs[i] = inp[((size_t)(b0 + j) * T_STEPS + t) * FEAT + f];
    }
    __syncthreads();

    float bv[4];
    #pragma unroll
    for (int c = 0; c < 4; ++c) bv[c] = bias[tid + c * 256];

    float acc[8][4];
    #pragma unroll
    for (int j = 0; j < 8; ++j)
        #pragma unroll
        for (int c = 0; c < 4; ++c) acc[j][c] = bv[c];

    for (int f = 0; f < FEAT; ++f) {
        float w0 = W[(size_t)f * UNITS + tid];
        float w1 = W[(size_t)f * UNITS + tid + 256];
        float w2 = W[(size_t)f * UNITS + tid + 512];
        float w3 = W[(size_t)f * UNITS + tid + 768];
        #pragma unroll
        for (int j = 0; j < 8; ++j) {
            float xv = xs[j * FEAT + f];
            acc[j][0] += xv * w0;
            acc[j][1] += xv * w1;
            acc[j][2] += xv * w2;
            acc[j][3] += xv * w3;
        }
    }

    #pragma unroll
    for (int j = 0; j < 8; ++j)
        #pragma unroll
        for (int c = 0; c < 4; ++c)
            xW[((size_t)t * BATCH + b0 + j) * UNITS + tid + c * 256] = acc[j][c];
}

// ---------------------------------------------------------------------------
// XCD-local MFMA scan with guaranteed agent-scope fallback.
// 256 blocks x 512 threads (cooperative, co-resident, 1 block/CU).
// Static roles: g = blockIdx&7 (g<4 worker, else spare-exit), slot = blockIdx>>3.
// Group g owns rows [g*16,+16) (row = dir*32+b); slot owns cols [slot*32,+32).
// Wave kq reads k-slice [kq*128,+128) written by slots 4kq..4kq+3; across the
// 8 waves every block observes all 32 member flags each step (skew <= 1 step,
// used by the demotion-republish proof below).
// LOCAL mode: tile/flag via plain stores (dirty in home L2) + sc0 loads.
// Safety nets (any failure degrades to the round-5 agent path, never hangs):
//  (a) startup verify via HW_REG_XCC_ID through agent memory; mismatch ->
//      agent mode from t=0.
//  (b) sc0 polls carry a timeout; on expiry the wave sets DEMOTE[g] (agent),
//      republishes its own sb tile + flag at agent scope (sc0 re-read of own
//      L2 -> agent store, bit-identical values), and goes agent forever.
//  (c) writers check DEMOTE[g] once/step; on transition republish sb tile and
//      switch to PAIRED plain+agent stores (keeps home-L2 dirty lines value-
//      equal to the coherence point, so later evictions can't clobber newer
//      agent data). Stuck readers need only tiles {t-1, t}: sb republish + the
//      current paired db stores cover exactly that.
__global__ __launch_bounds__(512) void rnn_scan(
        const float* __restrict__ xW,
        const u16* __restrict__ Ut1, const u16* __restrict__ Ut2,
        const u16* __restrict__ Ut3,
        float* __restrict__ hbuf, float* __restrict__ finbuf,
        u32* __restrict__ ctrl, float* __restrict__ out) {
    __shared__ f32x4 red[14][64];
    __shared__ u32 s_mode, s_dem;

    const int tid = threadIdx.x;
    const int bk  = blockIdx.x;
    const int gg  = bk & 7;
    if (gg >= 4) return;             // spare block
    const int g    = gg;
    const int slot = bk >> 3;        // 0..31
    const int lane = tid & 63;
    const int kq   = tid >> 6;       // wave 0..7
    const int quad = lane >> 4;
    const int n16  = lane & 15;
    const int R0   = g * 16;
    const int u0   = slot * 32;
    const int dir  = g >> 1;

    u32* flags  = ctrl + C_FLAGS;
    u32* myflag = flags + g * 32 + slot;
    const u32* fpoll = flags + g * 32 + kq * 4;   // 16B aligned

    // ---------------- verify phase: is this group really on one XCD? -------
    int xcd;
    asm volatile("s_getreg_b32 %0, hwreg(HW_REG_XCC_ID)" : "=s"(xcd));
    xcd &= 7;
    if (tid == 0) {
        st_agent_u32(ctrl + C_LOC + g * 32 + slot, (xcd == g) ? 1u : 2u);
        __hip_atomic_fetch_add(ctrl + C_NDONE, 1u, __ATOMIC_RELAXED,
                               __HIP_MEMORY_SCOPE_AGENT);
        while (ld_agent_u32(ctrl + C_NDONE) < 128u) __builtin_amdgcn_s_sleep(2);
        u32 ok = 1;
        for (int i = 0; i < 32; ++i)
            if (ld_agent_u32(ctrl + C_LOC + g * 32 + i) != 1u) ok = 0;
        s_mode = ok ? 0u : 1u;       // 0 = local fast path, 1 = agent
        s_dem = 0u;
    }
    __syncthreads();
    bool stick = false;              // per-wave sticky demotion

    // --- B fragments: U splits, 96 VGPRs, loaded once ---
    short8 bfr[4][2][3];
    #pragma unroll
    for (int ks = 0; ks < 4; ++ks) {
        const int koff = kq * 128 + ks * 32 + quad * 8;
        #pragma unroll
        for (int nq = 0; nq < 2; ++nq) {
            const size_t ub = (size_t)(u0 + nq * 16 + n16) * UNITS + koff;
            bfr[ks][nq][0] = ld_agent_b16x8(Ut1 + ub);
            bfr[ks][nq][1] = ld_agent_b16x8(Ut2 + ub);
            bfr[ks][nq][2] = ld_agent_b16x8(Ut3 + ub);
        }
    }

    // --- zero own tile of buffer 0, publish flag = 1 ---
    {
        const bool am0 = (s_mode != 0);
        const int zr = tid >> 5, zc = tid & 31;
        float* zp = hbuf + (size_t)(R0 + zr) * UNITS + u0 + zc;
        st_plain_f(zp, 0.f);
        if (am0) st_agent_f(zp, 0.f);
    }
    __syncthreads();                 // vmcnt(0): zeros committed before flag
    if (tid == 0) {
        st_plain_u32(myflag, 1u);
        if (s_mode != 0) st_agent_u32(myflag, 1u);
    }

    const size_t HS = (size_t)64 * UNITS;

    for (int t = 0; t < T_STEPS; ++t) {
        const size_t sb = (size_t)(t & 1) * HS;
        const size_t db = sb ^ HS;
        const u32 tgt = (u32)(t + 1);
        const bool am = (s_mode != 0);

        // demote check hoisted to step top (latency hidden); kq0 consumes later
        if (tid == 0) s_dem = ld_agent_u32(ctrl + C_DEMOTE + g);

        // xW prefetch (combining wave only)
        float xp[2][4];
        if (kq == 0) {
            const int xt = dir ? (T_STEPS - 1 - t) : t;
            #pragma unroll
            for (int nq = 0; nq < 2; ++nq)
                #pragma unroll
                for (int j = 0; j < 4; ++j) {
                    const int b = (R0 + quad * 4 + j) & 31;
                    xp[nq][j] = xW[(size_t)xt * (BATCH * UNITS) +
                                   (size_t)b * UNITS + u0 + nq * 16 + n16];
                }
        }

        // ---- poll the 4 source-writer flags ----
        bool am_eff = am || stick;
        if (!am_eff) {
            int tries = 0;
            for (;;) {
                u32x4 f = ld_sc0_u32x4(fpoll);
                if (f.x >= tgt && f.y >= tgt && f.z >= tgt && f.w >= tgt) break;
                if (++tries > POLL_TIMEOUT) {   // demote: republish own sb tile
                    st_agent_u32(ctrl + C_DEMOTE + g, 1u);
                    #pragma unroll
                    for (int j = 0; j < 8; ++j) {
                        int e = lane * 8 + j;          // 0..511
                        int r = e >> 5, c = e & 31;
                        float* p = hbuf + sb + (size_t)(R0 + r) * UNITS + u0 + c;
                        st_agent_f(p, ld_sc0_f(p));
                    }
                    __builtin_amdgcn_s_waitcnt(0);
                    if (lane == 0) st_agent_u32(myflag, tgt);
                    stick = true; am_eff = true;
                    break;
                }
            }
        }
        if (am_eff) {
            const u64* sf = (const u64*)fpoll;
            for (;;) {
                u64 qa = ld_agent_u64(sf), qb = ld_agent_u64(sf + 1);
                if ((u32)qa >= tgt && (u32)(qa >> 32) >= tgt &&
                    (u32)qb >= tgt && (u32)(qb >> 32) >= tgt) break;
                __builtin_amdgcn_s_sleep(1);
            }
        }

        // ---- load A (16 rows x this wave's 128 k), split, MFMA ----
        union HU { f32x4 v4[2]; u64 q[2]; float f[8]; u32 u[8]; } hu[4];
        const float* ab = hbuf + sb + (size_t)(R0 + n16) * UNITS + kq * 128 + quad * 8;
        if (!am_eff) {
            Q8 q8 = ld_sc0_q8(ab);
            hu[0].v4[0] = q8.a; hu[0].v4[1] = q8.b;
            hu[1].v4[0] = q8.c; hu[1].v4[1] = q8.d;
            hu[2].v4[0] = q8.e; hu[2].v4[1] = q8.f;
            hu[3].v4[0] = q8.g; hu[3].v4[1] = q8.h;
        } else {
            #pragma unroll
            for (int ks = 0; ks < 4; ++ks) {
                const u64* sp = (const u64*)(ab + ks * 32);
                hu[ks].q[0] = ld_agent_u64(sp);
                hu[ks].q[1] = ld_agent_u64(sp + 1);
                const u64* sp2 = sp + 2;
                ((u64*)&hu[ks].v4[1])[0] = ld_agent_u64(sp2);
                ((u64*)&hu[ks].v4[1])[1] = ld_agent_u64(sp2 + 1);
            }
        }

        f32x4 acc[2][2] = {{{0.f,0.f,0.f,0.f},{0.f,0.f,0.f,0.f}},
                           {{0.f,0.f,0.f,0.f},{0.f,0.f,0.f,0.f}}};
        #pragma unroll
        for (int ks = 0; ks < 4; ++ks) {
            short8 a1, a2, a3;
            #pragma unroll
            for (int j = 0; j < 8; ++j) {
                u32 xb = hu[ks].u[j];
                float x = __uint_as_float(xb);
                u16 s1 = (u16)(xb >> 16);
                float r1 = x - bf16_f(s1);
                u16 s2 = (u16)(__float_as_uint(r1) >> 16);
                float r2 = r1 - bf16_f(s2);
                u16 s3 = (u16)(__float_as_uint(r2) >> 16);
                a1[j] = (short)s1; a2[j] = (short)s2; a3[j] = (short)s3;
            }
            #pragma unroll
            for (int nq = 0; nq < 2; ++nq) {
                acc[nq][0] = __builtin_amdgcn_mfma_f32_16x16x32_bf16(a1, bfr[ks][nq][0], acc[nq][0], 0, 0, 0);
                acc[nq][1] = __builtin_amdgcn_mfma_f32_16x16x32_bf16(a2, bfr[ks][nq][0], acc[nq][1], 0, 0, 0);
                acc[nq][0] = __builtin_amdgcn_mfma_f32_16x16x32_bf16(a1, bfr[ks][nq][1], acc[nq][0], 0, 0, 0);
                acc[nq][1] = __builtin_amdgcn_mfma_f32_16x16x32_bf16(a2, bfr[ks][nq][1], acc[nq][1], 0, 0, 0);
                acc[nq][0] = __builtin_amdgcn_mfma_f32_16x16x32_bf16(a1, bfr[ks][nq][2], acc[nq][0], 0, 0, 0);
                acc[nq][1] = __builtin_amdgcn_mfma_f32_16x16x32_bf16(a3, bfr[ks][nq][0], acc[nq][1], 0, 0, 0);
            }
        }
        f32x4 c0 = acc[0][0] + acc[0][1];
        f32x4 c1 = acc[1][0] + acc[1][1];

        // ---- cross-wave k-reduction (round-5 layout: 0 bank conflicts) ----
        if (kq) {
            red[(kq - 1) * 2 + 0][lane] = c0;
            red[(kq - 1) * 2 + 1][lane] = c1;
        }
        __syncthreads();
        if (kq == 0) {
            #pragma unroll
            for (int w = 0; w < 7; ++w) {
                c0 += red[w * 2 + 0][lane];
                c1 += red[w * 2 + 1][lane];
            }
            const bool dem = (s_dem != 0);
            const bool pub_agent = am || stick || dem;
            if (!am && dem) {        // transition: republish sb tile agent
                #pragma unroll
                for (int j = 0; j < 8; ++j) {
                    int e = lane * 8 + j;
                    int r = e >> 5, c = e & 31;
                    float* p = hbuf + sb + (size_t)(R0 + r) * UNITS + u0 + c;
                    st_agent_f(p, ld_sc0_f(p));
                }
            }
            float* hdst = hbuf + db;
            #pragma unroll
            for (int nq = 0; nq < 2; ++nq)
                #pragma unroll
                for (int j = 0; j < 4; ++j) {
                    float a = (nq ? c1[j] : c0[j]) + xp[nq][j];
                    a = fminf(fmaxf(a, 0.f), CLIPV);
                    float* dp = hdst + (size_t)(R0 + quad * 4 + j) * UNITS +
                                u0 + nq * 16 + n16;
                    st_plain_f(dp, a);          // paired: keeps L2 == CP value
                    if (pub_agent) st_agent_f(dp, a);
                }
            if (lane == 0 && dem) s_mode = 1u;  // block-wide demote next step
        }
        __syncthreads();             // drains kq0 stores + publishes s_mode
        if (tid == 0) {
            st_plain_u32(myflag, (u32)(t + 2));
            if (s_mode != 0 || stick) st_agent_u32(myflag, (u32)(t + 2));
        }
    }

    // ---- final: push own tile (buffer 0) to agent-visible finbuf ----
    {
        const bool amf = (s_mode != 0) || stick;
        const int r = tid >> 5, c = tid & 31;
        const size_t off = (size_t)(R0 + r) * UNITS + u0 + c;
        float v = amf ? ld_agent_f(hbuf + off) : ld_sc0_f(hbuf + off);
        st_agent_f(finbuf + off, v);
    }
    __syncthreads();                 // drain agent stores
    if (tid == 0)
        __hip_atomic_fetch_add(ctrl + C_FINDONE, 1u, __ATOMIC_RELAXED,
                               __HIP_MEMORY_SCOPE_AGENT);

    if (g < 2) {                     // forward groups write the output
        if (tid == 0)
            while (ld_agent_u32(ctrl + C_FINDONE) < 128u)
                __builtin_amdgcn_s_sleep(1);
        __syncthreads();
        const int r = tid >> 5, c = tid & 31;
        const int b = R0 + r;
        float hf = ld_agent_f(finbuf + (size_t)b * UNITS + u0 + c);
        float hb = ld_agent_f(finbuf + (size_t)(b + 32) * UNITS + u0 + c);
        out[(size_t)b * UNITS + u0 + c] = hf + hb;
    }
}

// ---------------------------------------------------------------------------
extern "C" void kernel_launch(void* const* d_in, const int* in_sizes, int n_in,
                              void* d_out, int out_size, void* d_ws, size_t ws_size,
                              hipStream_t stream) {
    const float* inp  = (const float*)d_in[0];   // [32][800][161]
    const float* W    = (const float*)d_in[1];   // [161][1024]
    const float* U    = (const float*)d_in[2];   // [1024][1024]
    const float* bias = (const float*)d_in[3];   // [1024]
    float* out = (float*)d_out;                  // [32][1024]

    u16*   Ut1 = (u16*)d_ws;                              // 3 x 2 MB bf16 planes
    u16*   Ut2 = Ut1 + (size_t)UNITS * UNITS;
    u16*   Ut3 = Ut2 + (size_t)UNITS * UNITS;
    float* xW  = (float*)(Ut3 + (size_t)UNITS * UNITS);   // 104.9 MB
    float* hbuf   = xW + (size_t)T_STEPS * BATCH * UNITS; // 2 x 256 KB
    float* finbuf = hbuf + (size_t)2 * 64 * UNITS;        // 256 KB
    u32*   ctrl   = (u32*)(finbuf + (size_t)64 * UNITS);  // 2 KB

    init_ws<<<2, 256, 0, stream>>>(ctrl);
    u_split_t<<<dim3(32, 32), 256, 0, stream>>>(U, Ut1, Ut2, Ut3);
    xw_gemm<<<dim3(800, 4), 256, 0, stream>>>(inp, W, bias, xW);

    void* args[] = {(void*)&xW, (void*)&Ut1, (void*)&Ut2, (void*)&Ut3,
                    (void*)&hbuf, (void*)&finbuf, (void*)&ctrl, (void*)&out};
    hipLaunchCooperativeKernel((const void*)rnn_scan, dim3(256), dim3(512),
                               args, 0, stream);
}